// Round 7
// baseline (140.205 us; speedup 1.0000x reference)
//
#include <hip/hip_runtime.h>
#include <hip/hip_bf16.h>

typedef __bf16 bf16x8 __attribute__((ext_vector_type(8)));
typedef float  f32x4  __attribute__((ext_vector_type(4)));

// ---------------------------------------------------------------------------
// Stage 1: qkv = kern_tok @ qkv_w + qkv_b ; split into q(scaled),k,v
// ---------------------------------------------------------------------------
__global__ __launch_bounds__(192) void qkv_kernel(
    const float* __restrict__ conv_w, const float* __restrict__ qkv_w,
    const float* __restrict__ qkv_b,
    float* __restrict__ qv, float* __restrict__ kvv, float* __restrict__ vv)
{
    __shared__ float tok[64];
    const int bid = blockIdx.x;          // co*36 + s
    const int co = bid / 36, s = bid - co * 36;
    const int w = s / 9, p = s - w * 9;
    const int t = threadIdx.x;           // 192
    if (t < 64) tok[t] = conv_w[(((w * 64 + co) * 64 + t) * 9) + p];
    __syncthreads();
    float acc = qkv_b[t];
#pragma unroll 8
    for (int ci = 0; ci < 64; ++ci) acc += tok[ci] * qkv_w[ci * 192 + t];
    const int trip = t >> 6, rem = t & 63, h = rem >> 3, d = rem & 7;
    if (trip == 0) acc *= 0.35355339059327373f;   // hd^-0.5, hd=8
    float* dst = (trip == 0) ? qv : ((trip == 1) ? kvv : vv);
    dst[((co * 8 + h) * 36 + s) * 8 + d] = acc;
}

// ---------------------------------------------------------------------------
// Stage 2: attention per (co, head): softmax(q k^T) v  -> ao[co][s][h*8+d]
// ---------------------------------------------------------------------------
__global__ __launch_bounds__(64) void attn_kernel(
    const float* __restrict__ qv, const float* __restrict__ kvv,
    const float* __restrict__ vv, float* __restrict__ ao)
{
    __shared__ float kl[288], vl[288];
    const int bid = blockIdx.x;          // co*8 + h
    const int t = threadIdx.x;           // 64
    const float* kb = kvv + bid * 288;
    const float* vb = vv + bid * 288;
    for (int i = t; i < 288; i += 64) { kl[i] = kb[i]; vl[i] = vb[i]; }
    __syncthreads();
    if (t < 36) {
        float q[8];
        const float* qb = qv + bid * 288 + t * 8;
#pragma unroll
        for (int d = 0; d < 8; ++d) q[d] = qb[d];
        float sc[36];
        float mx = -1e30f;
#pragma unroll
        for (int u = 0; u < 36; ++u) {
            float a = 0.f;
#pragma unroll
            for (int d = 0; d < 8; ++d) a += q[d] * kl[u * 8 + d];
            sc[u] = a;
            mx = fmaxf(mx, a);
        }
        float sum = 0.f;
        float o[8] = {0.f,0.f,0.f,0.f,0.f,0.f,0.f,0.f};
#pragma unroll
        for (int u = 0; u < 36; ++u) {
            float e = expf(sc[u] - mx);
            sum += e;
#pragma unroll
            for (int d = 0; d < 8; ++d) o[d] += e * vl[u * 8 + d];
        }
        const float inv = 1.0f / sum;
        const int co = bid >> 3, h = bid & 7;
        float* dst = ao + (co * 36 + t) * 64 + h * 8;
#pragma unroll
        for (int d = 0; d < 8; ++d) dst[d] = o[d] * inv;
    }
}

// ---------------------------------------------------------------------------
// Stage 3: proj + SE + write bf16 kernels.
// kout layout: [((h*4 + w)*9 + p)][co][ci32]  (4 KB chunks = one
// (tap, ci-half)). conv reads each lane's 16 B slice directly into regs.
// ---------------------------------------------------------------------------
__global__ __launch_bounds__(64) void proj_se_kernel(
    const float* __restrict__ ao, const float* __restrict__ proj_w,
    const float* __restrict__ proj_b,
    const float* __restrict__ se_w1, const float* __restrict__ se_b1,
    const float* __restrict__ se_w2, const float* __restrict__ se_b2,
    ushort* __restrict__ kout)
{
    __shared__ float al[9][64];
    __shared__ float pool[64];
    __shared__ float hb[4];
    const int bid = blockIdx.x;          // w*64 + co
    const int w = bid >> 6, co = bid & 63;
    const int t = threadIdx.x;           // 64 (= ci)
    for (int i = t; i < 576; i += 64) {
        int p = i >> 6, j = i & 63;
        al[p][j] = ao[(co * 36 + w * 9 + p) * 64 + j];
    }
    __syncthreads();
    float kv[9];
#pragma unroll
    for (int p = 0; p < 9; ++p) {
        float a = proj_b[t];
#pragma unroll 8
        for (int j = 0; j < 64; ++j) a += al[p][j] * proj_w[j * 64 + t];
        kv[p] = a;
    }
    float pl = 0.f;
#pragma unroll
    for (int p = 0; p < 9; ++p) pl += kv[p];
    pool[t] = pl * (1.0f / 9.0f);
    __syncthreads();
    if (t < 4) {
        float hh = se_b1[w * 4 + t];
#pragma unroll 8
        for (int c = 0; c < 64; ++c) hh += pool[c] * se_w1[(w * 4 + t) * 64 + c];
        hb[t] = fmaxf(hh, 0.0f);
    }
    __syncthreads();
    float z = se_b2[w * 64 + t];
#pragma unroll
    for (int d = 0; d < 4; ++d) z += hb[d] * se_w2[(w * 64 + t) * 4 + d];
    const float sg = 1.0f / (1.0f + expf(-z));
    const int hhalf = t >> 5, ci32 = t & 31;
#pragma unroll
    for (int p = 0; p < 9; ++p) {
        __hip_bfloat16 hv = __float2bfloat16(kv[p] * sg);
        kout[(((hhalf * 4 + w) * 9) + p) * 2048 + co * 32 + ci32] = *(const ushort*)&hv;
    }
}

// ---------------------------------------------------------------------------
// Stage 4: dynamic per-window 3x3 conv, implicit GEMM, bf16 MFMA.
//
// Round-7: kern in REGISTERS, barrier-free main loop. R6's counted-vmcnt
// pipeline still locksteps all 4 waves 18x per block (s_barrier + vmcnt
// alignment on the slowest kern load) -- the barrier exists only because
// kern transits LDS. But kern is L2-resident (72-144 KB per XCD with the
// remap) and each wave's per-stage need is 4 contiguous 16 B slices.
// So: modulo-3 register set K[3][4] (fully unrolled loop => all indices
// compile-time, NO copies -- set (s-1)%3 is dead exactly when load s+2
// wants it; this is what R1 got wrong with its Bcur=Bnext copies that the
// compiler folded). Prefetch depth 2 => auto-waitcnt vmcnt(8) with two
// full stages (~400+ cyc of MFMA+ds_read) between issue and use.
//  - ZERO barriers between staging and epilogue (in_lds is read-only):
//    waves drift freely, stalls decorrelate across 12 waves/CU.
//  - LDS 41472 B (in_lds only) -> 3 blocks/CU.
//  - Per-stage LDS reads halve (4 Af b128/wave, no Kf): LDS-pipe cost
//    578 cyc/CU-stage vs R6's 1156.
//  - kern swizzle machinery deleted (registers don't bank-conflict).
// ---------------------------------------------------------------------------
__global__ __launch_bounds__(256, 3) void conv_kernel(
    const float* __restrict__ x, const ushort* __restrict__ kern,
    float* __restrict__ out)
{
    __shared__ alignas(16) ushort in_lds[18 * 18 * 64];   // 41472 B

    const int tid = threadIdx.x;

    // ---- XCD-chunked bijective remap: XCD k processes nb in [k*256,(k+1)*256)
    const int bid = blockIdx.x;                 // 0..2047, xcd = bid & 7
    const int nb  = ((bid & 7) << 8) + (bid >> 3);
    const int bz  = nb >> 6;                    // (w*8+b), 4 per XCD
    const int rem = nb & 63;
    const int i0  = (rem >> 3) << 4;
    const int j0  = (rem & 7) << 4;
    const int w = bz >> 3, b = bz & 7;
    const int gi = w >> 1, gj = w & 1;

    const int wv   = tid >> 6;
    const int lane = tid & 63;
    const int l15  = lane & 15;
    const int hi4  = lane >> 4;        // 0..3

    // ---- per-lane kern base: chunk s=(p=s>>1,hh=s&1) at
    // kern + (((hh*4+w)*9)+p)*2048 ushorts; lane slice (nf*16+l15)*32 + hi4*8.
    const ushort* kwl = kern + l15 * 32 + hi4 * 8;
    auto kchunk = [&](int s) -> const ushort* {
        const int p = s >> 1, hh = s & 1;
        return kwl + ((((hh * 4 + w) * 9) + p) << 11);
    };

    bf16x8 K[3][4];

    // ---- issue kern stages 0,1 register loads FIRST (their latency hides
    // under the input staging burst)
    {
        const ushort* g0 = kchunk(0);
        const ushort* g1 = kchunk(1);
#pragma unroll
        for (int nf = 0; nf < 4; ++nf) K[0][nf] = *(const bf16x8*)(g0 + nf * 512);
#pragma unroll
        for (int nf = 0; nf < 4; ++nf) K[1][nf] = *(const bf16x8*)(g1 + nf * 512);
    }

    // ---- input staging, FULL 64 channels: 18x18 px * 128 B, 16 thr/px.
    // All 21 clamped float4 loads issued before the cvt/write pass.
    // LDS position: (pp<<7) + ((cc*2) ^ ((q&7)<<4))  [0-conflict swizzle]
    {
        const int cc = (tid & 15) << 2;    // channel 0..60
        const int p0 = tid >> 4;           // 0..15
        float4 v[21];
        unsigned okm = 0;
#pragma unroll
        for (int k = 0; k < 21; ++k) {
            const int pp = p0 + (k << 4);          // <= 335
            const int ppc = pp < 323 ? pp : 323;
            const int r = ppc / 18, q = ppc - r * 18;
            const int iy = i0 - 1 + r, jx = j0 - 1 + q;
            const bool ok = (pp < 324) & (iy >= 0) & (iy < 128) & (jx >= 0) & (jx < 128);
            const int iyc = iy < 0 ? 0 : (iy > 127 ? 127 : iy);
            const int jxc = jx < 0 ? 0 : (jx > 127 ? 127 : jx);
            const size_t xi = (((size_t)b << 16) +
                               (size_t)(gi * 128 + iyc) * 256 + (size_t)(gj * 128 + jxc)) * 64 + cc;
            v[k] = *(const float4*)(x + xi);
            okm |= (unsigned)ok << k;
        }
#pragma unroll
        for (int k = 0; k < 21; ++k) {
            const int pp = p0 + (k << 4);
            if (pp < 324) {
                const int r = pp / 18, q = pp - r * 18;
                float4 z = (okm >> k) & 1 ? v[k] : make_float4(0.f, 0.f, 0.f, 0.f);
                union { ushort4 u; ushort h4[4]; } tmp;
                __hip_bfloat16 b0 = __float2bfloat16(z.x); tmp.h4[0] = *(const ushort*)&b0;
                __hip_bfloat16 b1 = __float2bfloat16(z.y); tmp.h4[1] = *(const ushort*)&b1;
                __hip_bfloat16 b2 = __float2bfloat16(z.z); tmp.h4[2] = *(const ushort*)&b2;
                __hip_bfloat16 b3 = __float2bfloat16(z.w); tmp.h4[3] = *(const ushort*)&b3;
                *(ushort4*)((char*)in_lds +
                    ((pp << 7) + ((cc << 1) ^ ((q & 7) << 4)))) = tmp.u;
            }
        }
    }

    f32x4 acc[4][4];
#pragma unroll
    for (int mf = 0; mf < 4; ++mf)
#pragma unroll
        for (int nf = 0; nf < 4; ++nf)
            acc[mf][nf] = (f32x4){0.f, 0.f, 0.f, 0.f};

    __syncthreads();     // input tile visible to all waves. LAST barrier
                         // until the epilogue.

#pragma unroll
    for (int s = 0; s < 18; ++s) {
        // prefetch stage s+2 into the register set last used at stage s-1
        // ((s+2) % 3 == (s-1) % 3): issue-before-compute gives ~2 stages
        // of latency window; compiler emits counted vmcnt before first use.
        if (s < 16) {
            const ushort* gs = kchunk(s + 2);
#pragma unroll
            for (int nf = 0; nf < 4; ++nf)
                K[(s + 2) % 3][nf] = *(const bf16x8*)(gs + nf * 512);
        }

        const int p = s >> 1, hh = s & 1;
        const int kh = p / 3, kw = p - kh * 3;
        const int q = l15 + kw;
        const int swz = (q & 7) << 4;
        const int c2 = (hh << 6) | (hi4 << 4);
#pragma unroll
        for (int mf = 0; mf < 4; ++mf) {
            const int r = wv * 4 + mf + kh;
            bf16x8 Af = *(const bf16x8*)((const char*)in_lds +
                          (((r * 18 + q) << 7) + (c2 ^ swz)));
#pragma unroll
            for (int nf = 0; nf < 4; ++nf)
                acc[mf][nf] = __builtin_amdgcn_mfma_f32_16x16x32_bf16(
                    K[s % 3][nf], Af, acc[mf][nf], 0, 0, 0);
        }
    }

    __syncthreads();     // all waves done reading in_lds before overwrite

    // ---- LDS-transpose epilogue (wave-private 4 KB region). Plain cached
    // stores, 1 KB contiguous per wave-instruction.
    char* ep = (char*)in_lds + (wv << 12);
#pragma unroll
    for (int mf = 0; mf < 4; ++mf) {
        const int iloc = wv * 4 + mf;
        const size_t rowoff = ((size_t)b << 16) +
                              (size_t)(gi * 128 + i0 + iloc) * 256 + (size_t)(gj * 128 + j0);
        // scatter: lane(l15,hi4) holds co = nf*16+hi4*4+reg at pixel l15
#pragma unroll
        for (int nf = 0; nf < 4; ++nf) {
            const int off = (nf * 64 + hi4 * 16) ^ ((l15 & 7) << 4);
            *(f32x4*)(ep + l15 * 256 + off) = acc[mf][nf];
        }
        // gather: lane(l15,hi4) reads co-chunk l15 of pixel t*4+hi4
#pragma unroll
        for (int t = 0; t < 4; ++t) {
            const int px = t * 4 + hi4;
            f32x4 vv4 = *(const f32x4*)(ep + px * 256 + ((l15 << 4) ^ ((px & 7) << 4)));
            *(f32x4*)(out + (rowoff + px) * 64 + l15 * 4) = vv4;
        }
    }
}

// ---------------------------------------------------------------------------
extern "C" void kernel_launch(void* const* d_in, const int* in_sizes, int n_in,
                              void* d_out, int out_size, void* d_ws, size_t ws_size,
                              hipStream_t stream)
{
    const float* x      = (const float*)d_in[0];
    const float* conv_w = (const float*)d_in[1];
    const float* qkv_w  = (const float*)d_in[2];
    const float* qkv_b  = (const float*)d_in[3];
    const float* proj_w = (const float*)d_in[4];
    const float* proj_b = (const float*)d_in[5];
    const float* se_w1  = (const float*)d_in[6];
    const float* se_b1  = (const float*)d_in[7];
    const float* se_w2  = (const float*)d_in[8];
    const float* se_b2  = (const float*)d_in[9];
    float* out = (float*)d_out;

    float* qv = (float*)d_ws;            // 147456 f
    float* kv = qv + 147456;             // 147456 f
    float* vv = kv + 147456;             // 147456 f
    float* ao = vv + 147456;             // 147456 f
    ushort* kb = (ushort*)(ao + 147456); // 147456 u16  (total ~2.6 MB)

    hipLaunchKernelGGL(qkv_kernel, dim3(2304), dim3(192), 0, stream,
                       conv_w, qkv_w, qkv_b, qv, kv, vv);
    hipLaunchKernelGGL(attn_kernel, dim3(512), dim3(64), 0, stream, qv, kv, vv, ao);
    hipLaunchKernelGGL(proj_se_kernel, dim3(256), dim3(64), 0, stream,
                       ao, proj_w, proj_b, se_w1, se_b1, se_w2, se_b2, kb);
    hipLaunchKernelGGL(conv_kernel, dim3(2048), dim3(256), 0, stream, x, kb, out);
}

// Round 8
// 117.763 us; speedup vs baseline: 1.1906x; 1.1906x over previous
//
#include <hip/hip_runtime.h>
#include <hip/hip_bf16.h>

typedef __bf16 bf16x8 __attribute__((ext_vector_type(8)));
typedef float  f32x4  __attribute__((ext_vector_type(4)));

// ---------------------------------------------------------------------------
// Stage 1: qkv = kern_tok @ qkv_w + qkv_b ; split into q(scaled),k,v
// ---------------------------------------------------------------------------
__global__ __launch_bounds__(192) void qkv_kernel(
    const float* __restrict__ conv_w, const float* __restrict__ qkv_w,
    const float* __restrict__ qkv_b,
    float* __restrict__ qv, float* __restrict__ kvv, float* __restrict__ vv)
{
    __shared__ float tok[64];
    const int bid = blockIdx.x;          // co*36 + s
    const int co = bid / 36, s = bid - co * 36;
    const int w = s / 9, p = s - w * 9;
    const int t = threadIdx.x;           // 192
    if (t < 64) tok[t] = conv_w[(((w * 64 + co) * 64 + t) * 9) + p];
    __syncthreads();
    float acc = qkv_b[t];
#pragma unroll 8
    for (int ci = 0; ci < 64; ++ci) acc += tok[ci] * qkv_w[ci * 192 + t];
    const int trip = t >> 6, rem = t & 63, h = rem >> 3, d = rem & 7;
    if (trip == 0) acc *= 0.35355339059327373f;   // hd^-0.5, hd=8
    float* dst = (trip == 0) ? qv : ((trip == 1) ? kvv : vv);
    dst[((co * 8 + h) * 36 + s) * 8 + d] = acc;
}

// ---------------------------------------------------------------------------
// Stage 2: attention per (co, head): softmax(q k^T) v  -> ao[co][s][h*8+d]
// ---------------------------------------------------------------------------
__global__ __launch_bounds__(64) void attn_kernel(
    const float* __restrict__ qv, const float* __restrict__ kvv,
    const float* __restrict__ vv, float* __restrict__ ao)
{
    __shared__ float kl[288], vl[288];
    const int bid = blockIdx.x;          // co*8 + h
    const int t = threadIdx.x;           // 64
    const float* kb = kvv + bid * 288;
    const float* vb = vv + bid * 288;
    for (int i = t; i < 288; i += 64) { kl[i] = kb[i]; vl[i] = vb[i]; }
    __syncthreads();
    if (t < 36) {
        float q[8];
        const float* qb = qv + bid * 288 + t * 8;
#pragma unroll
        for (int d = 0; d < 8; ++d) q[d] = qb[d];
        float sc[36];
        float mx = -1e30f;
#pragma unroll
        for (int u = 0; u < 36; ++u) {
            float a = 0.f;
#pragma unroll
            for (int d = 0; d < 8; ++d) a += q[d] * kl[u * 8 + d];
            sc[u] = a;
            mx = fmaxf(mx, a);
        }
        float sum = 0.f;
        float o[8] = {0.f,0.f,0.f,0.f,0.f,0.f,0.f,0.f};
#pragma unroll
        for (int u = 0; u < 36; ++u) {
            float e = expf(sc[u] - mx);
            sum += e;
#pragma unroll
            for (int d = 0; d < 8; ++d) o[d] += e * vl[u * 8 + d];
        }
        const float inv = 1.0f / sum;
        const int co = bid >> 3, h = bid & 7;
        float* dst = ao + (co * 36 + t) * 64 + h * 8;
#pragma unroll
        for (int d = 0; d < 8; ++d) dst[d] = o[d] * inv;
    }
}

// ---------------------------------------------------------------------------
// Stage 3: proj + SE + write bf16 kernels.
// kout layout: [((h*4 + w)*9 + p)][co][ci32]  (4 KB chunks = one
// (tap, ci-half)). conv reads each lane's 16 B slice directly into regs.
// ---------------------------------------------------------------------------
__global__ __launch_bounds__(64) void proj_se_kernel(
    const float* __restrict__ ao, const float* __restrict__ proj_w,
    const float* __restrict__ proj_b,
    const float* __restrict__ se_w1, const float* __restrict__ se_b1,
    const float* __restrict__ se_w2, const float* __restrict__ se_b2,
    ushort* __restrict__ kout)
{
    __shared__ float al[9][64];
    __shared__ float pool[64];
    __shared__ float hb[4];
    const int bid = blockIdx.x;          // w*64 + co
    const int w = bid >> 6, co = bid & 63;
    const int t = threadIdx.x;           // 64 (= ci)
    for (int i = t; i < 576; i += 64) {
        int p = i >> 6, j = i & 63;
        al[p][j] = ao[(co * 36 + w * 9 + p) * 64 + j];
    }
    __syncthreads();
    float kv[9];
#pragma unroll
    for (int p = 0; p < 9; ++p) {
        float a = proj_b[t];
#pragma unroll 8
        for (int j = 0; j < 64; ++j) a += al[p][j] * proj_w[j * 64 + t];
        kv[p] = a;
    }
    float pl = 0.f;
#pragma unroll
    for (int p = 0; p < 9; ++p) pl += kv[p];
    pool[t] = pl * (1.0f / 9.0f);
    __syncthreads();
    if (t < 4) {
        float hh = se_b1[w * 4 + t];
#pragma unroll 8
        for (int c = 0; c < 64; ++c) hh += pool[c] * se_w1[(w * 4 + t) * 64 + c];
        hb[t] = fmaxf(hh, 0.0f);
    }
    __syncthreads();
    float z = se_b2[w * 64 + t];
#pragma unroll
    for (int d = 0; d < 4; ++d) z += hb[d] * se_w2[(w * 64 + t) * 4 + d];
    const float sg = 1.0f / (1.0f + expf(-z));
    const int hhalf = t >> 5, ci32 = t & 31;
#pragma unroll
    for (int p = 0; p < 9; ++p) {
        __hip_bfloat16 hv = __float2bfloat16(kv[p] * sg);
        kout[(((hhalf * 4 + w) * 9) + p) * 2048 + co * 32 + ci32] = *(const ushort*)&hv;
    }
}

// ---------------------------------------------------------------------------
// Stage 4: dynamic per-window 3x3 conv, implicit GEMM, bf16 MFMA.
//
// Round-8 = R6 (best, 84 us) + kern-in-REGISTERS, with R7's two failure
// modes fixed. R6's binding resource is the LDS read pipe (8 ds_read_b128
// per wave-stage x 12 waves x 18 stages; MfmaUtil 17 / VALUBusy 18 both
// idle on lgkm). Kern-in-regs halves loop LDS reads (4 Af only) and
// removes the 72 KB/block kern DMA. R7 failed because (a) the compiler
// SANK the K-prefetch loads to their use (VGPR stayed 84 -> serialized
// L2 latency per stage) and (b) barrier-free drift broke x locality
// (FETCH +50 MB). Fixes:
//  (a) sched_barrier(0) immediately after issuing each stage's 4 kern
//      loads: nothing crosses, loads can't sink, K[3][4] stays live
//      (+48 VGPR -- VGPR_Count ~140 is the success diagnostic).
//  (b) keep a raw per-stage s_barrier (NO waitcnt: kern no longer
//      transits LDS, no inter-wave dependency -- pure drift control,
//      restoring R6's L2/LLC reuse timing).
// ---------------------------------------------------------------------------
__global__ __launch_bounds__(256, 3) void conv_kernel(
    const float* __restrict__ x, const ushort* __restrict__ kern,
    float* __restrict__ out)
{
    __shared__ alignas(16) ushort in_lds[18 * 18 * 64];   // 41472 B

    const int tid = threadIdx.x;

    // ---- XCD-chunked bijective remap: XCD k processes nb in [k*256,(k+1)*256)
    const int bid = blockIdx.x;                 // 0..2047, xcd = bid & 7
    const int nb  = ((bid & 7) << 8) + (bid >> 3);
    const int bz  = nb >> 6;                    // (w*8+b), 4 per XCD
    const int rem = nb & 63;
    const int i0  = (rem >> 3) << 4;
    const int j0  = (rem & 7) << 4;
    const int w = bz >> 3, b = bz & 7;
    const int gi = w >> 1, gj = w & 1;

    const int wv   = tid >> 6;
    const int lane = tid & 63;
    const int l15  = lane & 15;
    const int hi4  = lane >> 4;        // 0..3

    // ---- per-lane kern base: chunk s=(p=s>>1,hh=s&1) at
    // kern + (((hh*4+w)*9)+p)*2048 ushorts; lane slice (nf*16+l15)*32 + hi4*8.
    const ushort* kwl = kern + l15 * 32 + hi4 * 8;
    auto kchunk = [&](int s) -> const ushort* {
        const int p = s >> 1, hh = s & 1;
        return kwl + ((((hh * 4 + w) * 9) + p) << 11);
    };

    bf16x8 K[3][4];

    // ---- issue kern stages 0,1 register loads FIRST (latency hides under
    // the input staging burst); pin them with sched_barrier so they can't
    // sink into the loop.
    {
        const ushort* g0 = kchunk(0);
        const ushort* g1 = kchunk(1);
#pragma unroll
        for (int nf = 0; nf < 4; ++nf) K[0][nf] = *(const bf16x8*)(g0 + nf * 512);
#pragma unroll
        for (int nf = 0; nf < 4; ++nf) K[1][nf] = *(const bf16x8*)(g1 + nf * 512);
        __builtin_amdgcn_sched_barrier(0);
    }

    // ---- input staging, FULL 64 channels: 18x18 px * 128 B, 16 thr/px.
    // All 21 clamped float4 loads issued before the cvt/write pass.
    // LDS position: (pp<<7) + ((cc*2) ^ ((q&7)<<4))  [0-conflict swizzle]
    {
        const int cc = (tid & 15) << 2;    // channel 0..60
        const int p0 = tid >> 4;           // 0..15
        float4 v[21];
        unsigned okm = 0;
#pragma unroll
        for (int k = 0; k < 21; ++k) {
            const int pp = p0 + (k << 4);          // <= 335
            const int ppc = pp < 323 ? pp : 323;
            const int r = ppc / 18, q = ppc - r * 18;
            const int iy = i0 - 1 + r, jx = j0 - 1 + q;
            const bool ok = (pp < 324) & (iy >= 0) & (iy < 128) & (jx >= 0) & (jx < 128);
            const int iyc = iy < 0 ? 0 : (iy > 127 ? 127 : iy);
            const int jxc = jx < 0 ? 0 : (jx > 127 ? 127 : jx);
            const size_t xi = (((size_t)b << 16) +
                               (size_t)(gi * 128 + iyc) * 256 + (size_t)(gj * 128 + jxc)) * 64 + cc;
            v[k] = *(const float4*)(x + xi);
            okm |= (unsigned)ok << k;
        }
#pragma unroll
        for (int k = 0; k < 21; ++k) {
            const int pp = p0 + (k << 4);
            if (pp < 324) {
                const int r = pp / 18, q = pp - r * 18;
                float4 z = (okm >> k) & 1 ? v[k] : make_float4(0.f, 0.f, 0.f, 0.f);
                union { ushort4 u; ushort h4[4]; } tmp;
                __hip_bfloat16 b0 = __float2bfloat16(z.x); tmp.h4[0] = *(const ushort*)&b0;
                __hip_bfloat16 b1 = __float2bfloat16(z.y); tmp.h4[1] = *(const ushort*)&b1;
                __hip_bfloat16 b2 = __float2bfloat16(z.z); tmp.h4[2] = *(const ushort*)&b2;
                __hip_bfloat16 b3 = __float2bfloat16(z.w); tmp.h4[3] = *(const ushort*)&b3;
                *(ushort4*)((char*)in_lds +
                    ((pp << 7) + ((cc << 1) ^ ((q & 7) << 4)))) = tmp.u;
            }
        }
    }

    f32x4 acc[4][4];
#pragma unroll
    for (int mf = 0; mf < 4; ++mf)
#pragma unroll
        for (int nf = 0; nf < 4; ++nf)
            acc[mf][nf] = (f32x4){0.f, 0.f, 0.f, 0.f};

    __syncthreads();     // input tile visible to all waves

#pragma unroll
    for (int s = 0; s < 18; ++s) {
        // drift-control barrier (raw: no waitcnt attached, no LDS dep)
        __builtin_amdgcn_s_barrier();

        // prefetch stage s+2 into the register set last used at stage s-1
        // ((s+2)%3 == (s-1)%3), then PIN with sched_barrier(0) so the
        // loads cannot sink to their use (R7's failure). ~2 stages of
        // MFMA+ds_read (~300+ cyc) covers the L2 round-trip.
        if (s < 16) {
            const ushort* gs = kchunk(s + 2);
#pragma unroll
            for (int nf = 0; nf < 4; ++nf)
                K[(s + 2) % 3][nf] = *(const bf16x8*)(gs + nf * 512);
        }
        __builtin_amdgcn_sched_barrier(0);

        const int p = s >> 1, hh = s & 1;
        const int kh = p / 3, kw = p - kh * 3;
        const int q = l15 + kw;
        const int swz = (q & 7) << 4;
        const int c2 = (hh << 6) | (hi4 << 4);
#pragma unroll
        for (int mf = 0; mf < 4; ++mf) {
            const int r = wv * 4 + mf + kh;
            bf16x8 Af = *(const bf16x8*)((const char*)in_lds +
                          (((r * 18 + q) << 7) + (c2 ^ swz)));
#pragma unroll
            for (int nf = 0; nf < 4; ++nf)
                acc[mf][nf] = __builtin_amdgcn_mfma_f32_16x16x32_bf16(
                    K[s % 3][nf], Af, acc[mf][nf], 0, 0, 0);
        }
    }

    __syncthreads();     // all waves done reading in_lds before overwrite

    // ---- LDS-transpose epilogue (wave-private 4 KB region). Plain cached
    // stores, 1 KB contiguous per wave-instruction.
    char* ep = (char*)in_lds + (wv << 12);
#pragma unroll
    for (int mf = 0; mf < 4; ++mf) {
        const int iloc = wv * 4 + mf;
        const size_t rowoff = ((size_t)b << 16) +
                              (size_t)(gi * 128 + i0 + iloc) * 256 + (size_t)(gj * 128 + j0);
        // scatter: lane(l15,hi4) holds co = nf*16+hi4*4+reg at pixel l15
#pragma unroll
        for (int nf = 0; nf < 4; ++nf) {
            const int off = (nf * 64 + hi4 * 16) ^ ((l15 & 7) << 4);
            *(f32x4*)(ep + l15 * 256 + off) = acc[mf][nf];
        }
        // gather: lane(l15,hi4) reads co-chunk l15 of pixel t*4+hi4
#pragma unroll
        for (int t = 0; t < 4; ++t) {
            const int px = t * 4 + hi4;
            f32x4 vv4 = *(const f32x4*)(ep + px * 256 + ((l15 << 4) ^ ((px & 7) << 4)));
            *(f32x4*)(out + (rowoff + px) * 64 + l15 * 4) = vv4;
        }
    }
}

// ---------------------------------------------------------------------------
extern "C" void kernel_launch(void* const* d_in, const int* in_sizes, int n_in,
                              void* d_out, int out_size, void* d_ws, size_t ws_size,
                              hipStream_t stream)
{
    const float* x      = (const float*)d_in[0];
    const float* conv_w = (const float*)d_in[1];
    const float* qkv_w  = (const float*)d_in[2];
    const float* qkv_b  = (const float*)d_in[3];
    const float* proj_w = (const float*)d_in[4];
    const float* proj_b = (const float*)d_in[5];
    const float* se_w1  = (const float*)d_in[6];
    const float* se_b1  = (const float*)d_in[7];
    const float* se_w2  = (const float*)d_in[8];
    const float* se_b2  = (const float*)d_in[9];
    float* out = (float*)d_out;

    float* qv = (float*)d_ws;            // 147456 f
    float* kv = qv + 147456;             // 147456 f
    float* vv = kv + 147456;             // 147456 f
    float* ao = vv + 147456;             // 147456 f
    ushort* kb = (ushort*)(ao + 147456); // 147456 u16  (total ~2.6 MB)

    hipLaunchKernelGGL(qkv_kernel, dim3(2304), dim3(192), 0, stream,
                       conv_w, qkv_w, qkv_b, qv, kv, vv);
    hipLaunchKernelGGL(attn_kernel, dim3(512), dim3(64), 0, stream, qv, kv, vv, ao);
    hipLaunchKernelGGL(proj_se_kernel, dim3(256), dim3(64), 0, stream,
                       ao, proj_w, proj_b, se_w1, se_b1, se_w2, se_b2, kb);
    hipLaunchKernelGGL(conv_kernel, dim3(2048), dim3(256), 0, stream, x, kb, out);
}